// Round 14
// baseline (10.450 us; speedup 1.0000x reference)
//
#include <hip/hip_runtime.h>
#include <hip/hip_bf16.h>

#define D_Z 64
#define D_TOTAL 16448
#define NY 16384
#define TJ 32
#define N_JCH (NY / TJ)      // 512
#define N_YB (N_JCH * 2)     // 1024 y-blocks (2 sample halves)
#define N_ZB 8

typedef __attribute__((ext_vector_type(8))) short bf16x8;
typedef __attribute__((ext_vector_type(4))) float f32x4;

__device__ __forceinline__ short f2bf(float x) {
    union { __hip_bfloat16 h; short s; } u;
    u.h = __float2bfloat16(x);   // RNE; pairs into v_cvt_pk_bf16_f32
    return u.s;
}

__device__ __forceinline__ bf16x8 packbf(float4 a, float4 b) {
    bf16x8 r = { f2bf(a.x), f2bf(a.y), f2bf(a.z), f2bf(a.w),
                 f2bf(b.x), f2bf(b.y), f2bf(b.z), f2bf(b.w) };
    return r;
}

// Grid: blocks 0..7 -> z-part (16 samples x 64 cols, MFMA).
//       blocks 8..1031 -> y-part: t = shalf*512 + jchunk;
//       64 samples x 32 y-cols per block -> 4 blocks/CU, 16 waves/CU
//       (halved per-block latency chain, doubled TLP vs R11).
__global__ __launch_bounds__(256, 4) void sv_kernel(
    const float* __restrict__ m,
    const float* __restrict__ Lz,     // tril(64), row-major tril order
    const float* __restrict__ Ly,     // N * 36, per-block tril(8)
    const float* __restrict__ Lyz,    // [NY x 64] row-major
    const float* __restrict__ eps,    // [128, 16448]
    float* __restrict__ out)          // [128, 16448]
{
    __shared__ __align__(16) short zs[64 * 64];   // eps_z half bf16 swz (8 KB)
    __shared__ __align__(16) short ys[64 * 32];   // eps_y tile bf16     (4 KB)
    __shared__ __align__(16) short ls[32 * 64];   // Lyz tile bf16       (4 KB)

    const int tid = threadIdx.x;
    const int bb  = blockIdx.x;

    char* zsb = (char*)zs;
    char* ysb = (char*)ys;
    char* lsb = (char*)ls;

    if (bb >= N_ZB) {
        // ================= y-part =================
        const int t      = bb - N_ZB;
        const int jchunk = t & (N_JCH - 1);
        const int shalf  = t >> 9;
        const int j0     = jchunk * TJ;
        const int s0     = shalf * 64;

        const int r0z = tid >> 3;          // 0..31
        const int c8z = (tid & 7) << 3;    // 0..56
        const int r0y = tid >> 2;          // 0..63
        const int c8y = (tid & 3) << 3;    // 0,8,16,24

        // ---- PHASE 1: issue ALL staging loads into registers ----
        float4 rz[2][2], rl[2], ry[2];
        #pragma unroll
        for (int it = 0; it < 2; ++it) {
            const float* p = eps + (size_t)(s0 + r0z + (it << 5)) * D_TOTAL + c8z;
            rz[it][0] = *(const float4*)p;
            rz[it][1] = *(const float4*)(p + 4);
        }
        {
            const float* q = Lyz + (size_t)(j0 + r0z) * D_Z + c8z;
            rl[0] = *(const float4*)q;
            rl[1] = *(const float4*)(q + 4);
        }
        {
            const float* p = eps + (size_t)(s0 + r0y) * D_TOTAL + D_Z + j0 + c8y;
            ry[0] = *(const float4*)p;
            ry[1] = *(const float4*)(p + 4);
        }

        // ---- independent per-lane loads (overlap with staging latency) ----
        const int w    = tid >> 6;         // wave 0..3 -> 16 local samples each
        const int lane = tid & 63;
        const int ln15 = lane & 15;
        const int lg   = lane >> 4;

        float  mj_[2];
        bf16x8 by_[2];
        #pragma unroll
        for (int st = 0; st < 2; ++st) {
            const int jy = j0 + (st << 4) + ln15;
            mj_[st] = m[D_Z + jy];
            const int r = ln15 & 7;
            const float* lyp = Ly + (size_t)(jy >> 3) * 36 + r * (r + 1) / 2;
            bf16x8 by = {0, 0, 0, 0, 0, 0, 0, 0};
            if (lg == (ln15 >> 3)) {
                float lyr[8];
                #pragma unroll
                for (int c = 0; c < 8; ++c) lyr[c] = (c <= r) ? lyp[c] : 0.0f;
                by = packbf(make_float4(lyr[0], lyr[1], lyr[2], lyr[3]),
                            make_float4(lyr[4], lyr[5], lyr[6], lyr[7]));
            }
            by_[st] = by;
        }

        // ---- PHASE 2: cvt + ds_write all staged tiles ----
        #pragma unroll
        for (int it = 0; it < 2; ++it) {
            const int row = r0z + (it << 5);          // 0..63 local
            *(bf16x8*)(zsb + row * 128 + ((c8z << 1) ^ ((row & 7) << 4))) =
                packbf(rz[it][0], rz[it][1]);
        }
        *(bf16x8*)(lsb + r0z * 128 + ((c8z << 1) ^ ((r0z & 7) << 4))) =
            packbf(rl[0], rl[1]);
        *(bf16x8*)(ysb + r0y * 64 + ((c8y << 1) ^ ((r0y & 3) << 4))) =
            packbf(ry[0], ry[1]);
        __syncthreads();

        // ---- A fragments (regs, reused across both subtiles) ----
        const int arow = (w << 4) + ln15;  // local sample row 0..63
        bf16x8 az[2];
        #pragma unroll
        for (int ks = 0; ks < 2; ++ks) {
            az[ks] = *(const bf16x8*)(zsb + arow * 128 +
                        (((ks << 6) + (lg << 4)) ^ ((arow & 7) << 4)));
        }
        bf16x8 ay[2];
        #pragma unroll
        for (int st = 0; st < 2; ++st) {
            ay[st] = *(const bf16x8*)(ysb + arow * 64 +
                        (((st << 5) + ((lg & 1) << 4)) ^ ((arow & 3) << 4)));
        }

        #pragma unroll
        for (int st = 0; st < 2; ++st) {
            const int jg = D_Z + j0 + (st << 4) + ln15;

            // B-z fragments from LDS Lyz panel
            const int brow = (st << 4) + ln15;
            bf16x8 bz[2];
            #pragma unroll
            for (int ks = 0; ks < 2; ++ks) {
                bz[ks] = *(const bf16x8*)(lsb + brow * 128 +
                            (((ks << 6) + (lg << 4)) ^ ((brow & 7) << 4)));
            }

            f32x4 acc = {0.f, 0.f, 0.f, 0.f};
            acc = __builtin_amdgcn_mfma_f32_16x16x32_bf16(az[0], bz[0], acc, 0, 0, 0);
            acc = __builtin_amdgcn_mfma_f32_16x16x32_bf16(az[1], bz[1], acc, 0, 0, 0);
            acc = __builtin_amdgcn_mfma_f32_16x16x32_bf16(ay[st], by_[st], acc, 0, 0, 0);

            const float mj = mj_[st];
            const int sbase = s0 + (w << 4) + (lg << 2);
            #pragma unroll
            for (int reg = 0; reg < 4; ++reg) {
                __builtin_nontemporal_store(acc[reg] + mj,
                    &out[(size_t)(sbase + reg) * D_TOTAL + jg]);
            }
        }
    } else {
        // ========== z-part: 16 samples x 64 cols via MFMA (R11 verbatim) ==========
        const int s0 = bb * 16;

        const int w    = tid >> 6;
        const int lane = tid & 63;
        const int ln15 = lane & 15;
        const int lg   = lane >> 4;
        const int j = (w << 4) + ln15;     // out col 0..63

        // stage load into regs first
        float4 sz0, sz1;
        const int row = (tid >> 3) & 15;
        const int c8  = (tid & 7) << 3;
        const bool do_stage = (tid < 128);
        if (do_stage) {
            const float* p = eps + (size_t)(s0 + row) * D_TOTAL + c8;
            sz0 = *(const float4*)p;
            sz1 = *(const float4*)(p + 4);
        }

        // B-frags: Lz row j, zero-masked beyond the triangle (k > j)
        const float* lzr = Lz + j * (j + 1) / 2;
        bf16x8 bz[2];
        #pragma unroll
        for (int ks = 0; ks < 2; ++ks) {
            float v[8];
            #pragma unroll
            for (int e = 0; e < 8; ++e) {
                const int k = (ks << 5) + (lg << 3) + e;
                v[e] = (k <= j) ? lzr[k] : 0.0f;
            }
            bz[ks] = packbf(make_float4(v[0], v[1], v[2], v[3]),
                            make_float4(v[4], v[5], v[6], v[7]));
        }

        if (do_stage) {
            *(bf16x8*)(zsb + row * 128 + ((c8 << 1) ^ ((row & 7) << 4))) =
                packbf(sz0, sz1);
        }
        __syncthreads();

        // A-frags: eps_z rows from LDS
        bf16x8 az[2];
        #pragma unroll
        for (int ks = 0; ks < 2; ++ks) {
            az[ks] = *(const bf16x8*)(zsb + ln15 * 128 +
                        (((ks << 6) + (lg << 4)) ^ ((ln15 & 7) << 4)));
        }

        f32x4 acc = {0.f, 0.f, 0.f, 0.f};
        acc = __builtin_amdgcn_mfma_f32_16x16x32_bf16(az[0], bz[0], acc, 0, 0, 0);
        acc = __builtin_amdgcn_mfma_f32_16x16x32_bf16(az[1], bz[1], acc, 0, 0, 0);

        const float mj = m[j];
        #pragma unroll
        for (int reg = 0; reg < 4; ++reg) {
            __builtin_nontemporal_store(acc[reg] + mj,
                &out[(size_t)(s0 + (lg << 2) + reg) * D_TOTAL + j]);
        }
    }
}

extern "C" void kernel_launch(void* const* d_in, const int* in_sizes, int n_in,
                              void* d_out, int out_size, void* d_ws, size_t ws_size,
                              hipStream_t stream) {
    const float* m   = (const float*)d_in[0];
    const float* Lz  = (const float*)d_in[1];
    const float* Ly  = (const float*)d_in[2];
    const float* Lyz = (const float*)d_in[3];
    const float* eps = (const float*)d_in[4];
    float* out = (float*)d_out;

    dim3 grid(N_ZB + N_YB);  // 1032
    dim3 block(256);
    hipLaunchKernelGGL(sv_kernel, grid, block, 0, stream,
                       m, Lz, Ly, Lyz, eps, out);
}